// Round 5
// baseline (135.177 us; speedup 1.0000x reference)
//
#include <hip/hip_runtime.h>

#define E_TOT 320000
#define NN    10000
#define DN    128
#define DE    32
#define DH    192
#define DO    128
#define EB    64
#define SHS   200   // s_h row stride in ushorts (400 B; 4-row bank step = 16 -> ~2-way max)

typedef __attribute__((ext_vector_type(8))) short bf16x8;
typedef __attribute__((ext_vector_type(4))) float f32x4;

// packed weight tables (rewritten every launch)
#define W1_FRAGS (8*12*64)    // B-frags of W1 node part (node_proj): kk(8) x nt(12) x lane
#define E_FRAGS  (12*64)      // A-frags of W1_edge^T (edge GEMM1): mt(12) x lane
#define W2_FRAGS (6*8*64)     // B-frags of W2: kk(6) x nt(8) x lane
#define FRAGS_TOT (W1_FRAGS + E_FRAGS + W2_FRAGS)
__device__ __align__(16) unsigned short g_p1[W1_FRAGS * 8];
__device__ __align__(16) unsigned short g_e [E_FRAGS * 8];
__device__ __align__(16) unsigned short g_p2[W2_FRAGS * 8];

__device__ __forceinline__ unsigned short f2bf(float f) {
    union { float f; unsigned u; } v; v.f = f;
    return (unsigned short)((v.u + 0x7FFFu + ((v.u >> 16) & 1u)) >> 16);
}
__device__ __forceinline__ float bflo(unsigned u) {
    union { unsigned v; float f; } t; t.v = u << 16; return t.f;
}
__device__ __forceinline__ float bfhi(unsigned u) {
    union { unsigned v; float f; } t; t.v = u & 0xFFFF0000u; return t.f;
}
__device__ __forceinline__ float tanh_fast(float x) {
    float ex = __expf(x + x);
    return 1.0f - 2.0f * __builtin_amdgcn_rcpf(ex + 1.0f);
}
__device__ __forceinline__ unsigned cvt_pk_bf16(float lo, float hi) {
    unsigned r;
    asm("v_cvt_pk_bf16_f32 %0, %1, %2" : "=v"(r) : "v"(lo), "v"(hi));
    return r;
}

// ---------------------------------------------------------------------------
// prep: pack all three weight tables + zero the output
// ---------------------------------------------------------------------------
__global__ void prep(const float* __restrict__ W1, const float* __restrict__ W2,
                     float* __restrict__ outz)
{
    int f = blockIdx.x * 256 + threadIdx.x;
    unsigned short tmp[8];
    if (f < W1_FRAGS) {                       // node-part B-frags: rows 0..255 of W1
        int kk = f / (12 * 64), nt = (f >> 6) % 12, lane = f & 63;
        int r0 = kk * 32 + ((lane >> 4) << 3);
        int c  = nt * 16 + (lane & 15);
        #pragma unroll
        for (int i = 0; i < 8; ++i) tmp[i] = f2bf(W1[(r0 + i) * DH + c]);
        *(uint4*)(g_p1 + (size_t)f * 8) = *(const uint4*)tmp;
    } else if (f < W1_FRAGS + E_FRAGS) {      // W1_edge^T A-frags: A[hid][k=edgedim]
        int f2 = f - W1_FRAGS;
        int mt = f2 >> 6, lane = f2 & 63;
        int k0 = ((lane >> 4) << 3);          // k = edge-feature dim
        int hid = mt * 16 + (lane & 15);
        #pragma unroll
        for (int i = 0; i < 8; ++i) tmp[i] = f2bf(W1[(256 + k0 + i) * DH + hid]);
        *(uint4*)(g_e + (size_t)f2 * 8) = *(const uint4*)tmp;
    } else if (f < FRAGS_TOT) {               // W2 B-frags
        int f3 = f - W1_FRAGS - E_FRAGS;
        int kk = f3 / (8 * 64), nt = (f3 >> 6) % 8, lane = f3 & 63;
        int r0 = kk * 32 + ((lane >> 4) << 3);
        int c  = nt * 16 + (lane & 15);
        #pragma unroll
        for (int i = 0; i < 8; ++i) tmp[i] = f2bf(W2[(r0 + i) * DO + c]);
        *(uint4*)(g_p2 + (size_t)f3 * 8) = *(const uint4*)tmp;
    } else {
        int z = f - FRAGS_TOT;
        if (z < NN * DO) outz[z] = 0.f;
    }
}

// ---------------------------------------------------------------------------
// node projections, bf16 out: P_s = n@W1[0:128]+b1 (y=0), P_r = n@W1[128:256] (y=1)
// ---------------------------------------------------------------------------
__global__ __launch_bounds__(256) void node_proj(
    const float* __restrict__ n_embed, const float* __restrict__ b1,
    unsigned short* __restrict__ P)
{
    __shared__ __align__(16) unsigned short s_a[64][136];
    const int tid  = threadIdx.x;
    const int half = blockIdx.y;
    const int n0   = blockIdx.x * 64;

    #pragma unroll
    for (int it = 0; it < 8; ++it) {
        int idx = tid + it * 256;
        int row = idx >> 5, c = idx & 31;
        float4 v = make_float4(0.f, 0.f, 0.f, 0.f);
        if (n0 + row < NN) v = ((const float4*)(n_embed + (size_t)(n0 + row) * DN))[c];
        unsigned t0 = cvt_pk_bf16(v.x, v.y), t1 = cvt_pk_bf16(v.z, v.w);
        *(uint2*)&s_a[row][c * 4] = make_uint2(t0, t1);
    }
    __syncthreads();

    const int lane = tid & 63, w = tid >> 6;
    const int arow = lane & 15, akb = (lane >> 4) * 8, rbase = (lane >> 4) * 4;

    f32x4 acc[4][3];
    #pragma unroll
    for (int mt = 0; mt < 4; ++mt)
        #pragma unroll
        for (int j = 0; j < 3; ++j) acc[mt][j] = (f32x4){0.f, 0.f, 0.f, 0.f};

    for (int kk = 0; kk < 4; ++kk) {
        bf16x8 a[4], b[3];
        #pragma unroll
        for (int mt = 0; mt < 4; ++mt)
            a[mt] = *(const bf16x8*)&s_a[mt * 16 + arow][kk * 32 + akb];
        #pragma unroll
        for (int j = 0; j < 3; ++j)
            b[j] = *(const bf16x8*)(g_p1 + (((size_t)(kk + 4 * half) * 12 + (3 * w + j)) * 64 + lane) * 8);
        #pragma unroll
        for (int mt = 0; mt < 4; ++mt)
            #pragma unroll
            for (int j = 0; j < 3; ++j)
                acc[mt][j] = __builtin_amdgcn_mfma_f32_16x16x32_bf16(a[mt], b[j], acc[mt][j], 0, 0, 0);
    }

    unsigned short* Pout = P + (size_t)half * NN * DH;
    float bj[3];
    #pragma unroll
    for (int j = 0; j < 3; ++j) bj[j] = (half == 0) ? b1[48 * w + 16 * j + arow] : 0.f;
    #pragma unroll
    for (int mt = 0; mt < 4; ++mt)
        #pragma unroll
        for (int j = 0; j < 3; ++j)
            #pragma unroll
            for (int r = 0; r < 4; ++r) {
                int row = n0 + mt * 16 + rbase + r;
                if (row < NN)
                    Pout[(size_t)row * DH + 48 * w + 16 * j + arow] = f2bf(acc[mt][j][r] + bj[j]);
            }
}

// ---------------------------------------------------------------------------
// fused edge kernel, transposed GEMM1 (h^T = W1e^T @ ef^T):
//   MFMA C-layout == consume layout -> tanh on accumulators, 2 barriers total,
//   register-space segment reduce (no s_msg).
// ---------------------------------------------------------------------------
__global__ __launch_bounds__(256, 4) void edge_mlp4(
    const float* __restrict__ e_embed,
    const int* __restrict__ senders, const int* __restrict__ receivers,
    const unsigned short* __restrict__ Ps, const unsigned short* __restrict__ Pr,
    const float* __restrict__ b2, float* __restrict__ out)
{
    __shared__ __align__(16) unsigned short s_e[EB][40];   // 5120 B
    __shared__ __align__(16) unsigned short s_h[EB][SHS];  // 25600 B
    __shared__ int s_send[EB];                             // 256 B

    const int tid  = threadIdx.x;
    const int nb8  = gridDim.x >> 3;
    const int e0   = (((blockIdx.x & 7) * nb8) + (blockIdx.x >> 3)) * EB;  // XCD swizzle
    const int lane = tid & 63, w = tid >> 6;
    const int arow = lane & 15, g = lane >> 4, akb = g * 8;

    // ---- phase 0: EARLY per-lane P gather (my edge = w*16+arow, hid mt*16+g*4+{0..3}) ----
    const int myedge = e0 + w * 16 + arow;
    const int sN = senders[myedge], rN = receivers[myedge];
    const unsigned short* psrow = Ps + (size_t)sN * DH;
    const unsigned short* prrow = Pr + (size_t)rN * DH;
    uint2 pv[12], qv[12];
    #pragma unroll
    for (int mt = 0; mt < 12; ++mt) {
        pv[mt] = *(const uint2*)(psrow + mt * 16 + g * 4);
        qv[mt] = *(const uint2*)(prrow + mt * 16 + g * 4);
    }
    const float bd0 = b2[32 * w + arow], bd1 = b2[32 * w + 16 + arow];

    if (tid < EB) s_send[tid] = senders[e0 + tid];
    #pragma unroll
    for (int it = 0; it < 2; ++it) {
        int idx = tid + it * 256;
        int row = idx >> 3, c = idx & 7;
        float4 v = ((const float4*)(e_embed + (size_t)(e0 + row) * DE))[c];
        unsigned t0 = cvt_pk_bf16(v.x, v.y), t1 = cvt_pk_bf16(v.z, v.w);
        *(uint2*)&s_e[row][c * 4] = make_uint2(t0, t1);
    }
    __syncthreads();

    // ---- phase 1: GEMM1^T (12 MFMAs, shared B-frag) + P add + tanh -> s_h ----
    {
        const bf16x8 bfrag = *(const bf16x8*)&s_e[w * 16 + arow][akb];
        #pragma unroll
        for (int mt = 0; mt < 12; ++mt) {
            bf16x8 af = *(const bf16x8*)(g_e + ((size_t)mt * 64 + lane) * 8);
            f32x4 z = (f32x4){0.f, 0.f, 0.f, 0.f};
            f32x4 acc = __builtin_amdgcn_mfma_f32_16x16x32_bf16(af, bfrag, z, 0, 0, 0);
            float t0 = tanh_fast(acc[0] + bflo(pv[mt].x) + bflo(qv[mt].x));
            float t1 = tanh_fast(acc[1] + bfhi(pv[mt].x) + bfhi(qv[mt].x));
            float t2 = tanh_fast(acc[2] + bflo(pv[mt].y) + bflo(qv[mt].y));
            float t3 = tanh_fast(acc[3] + bfhi(pv[mt].y) + bfhi(qv[mt].y));
            *(uint2*)&s_h[w * 16 + arow][mt * 16 + g * 4] =
                make_uint2(cvt_pk_bf16(t0, t1), cvt_pk_bf16(t2, t3));
        }
    }
    __syncthreads();

    // ---- phase 2: GEMM2  msg = h @ W2 (C-layout kept in registers) ----
    f32x4 acc2[4][2];
    #pragma unroll
    for (int mt = 0; mt < 4; ++mt)
        #pragma unroll
        for (int j = 0; j < 2; ++j) acc2[mt][j] = (f32x4){0.f, 0.f, 0.f, 0.f};

    for (int kk = 0; kk < 6; ++kk) {
        bf16x8 a[4], b[2];
        #pragma unroll
        for (int mt = 0; mt < 4; ++mt)
            a[mt] = *(const bf16x8*)&s_h[mt * 16 + arow][kk * 32 + akb];
        #pragma unroll
        for (int j = 0; j < 2; ++j)
            b[j] = *(const bf16x8*)(g_p2 + (((size_t)kk * 8 + (2 * w + j)) * 64 + lane) * 8);
        #pragma unroll
        for (int mt = 0; mt < 4; ++mt)
            #pragma unroll
            for (int j = 0; j < 2; ++j)
                acc2[mt][j] = __builtin_amdgcn_mfma_f32_16x16x32_bf16(a[mt], b[j], acc2[mt][j], 0, 0, 0);
    }

    // ---- phase 3: register-space segment reduce over sorted senders ----
    {
        const int col0 = 32 * w + arow, col1 = col0 + 16;
        float sum0 = 0.f, sum1 = 0.f;
        int cur = s_send[g * 4];
        #pragma unroll
        for (int mt = 0; mt < 4; ++mt)
            #pragma unroll
            for (int r = 0; r < 4; ++r) {
                int row = mt * 16 + g * 4 + r;
                int s = s_send[row];
                float v0 = acc2[mt][0][r] + bd0;
                float v1 = acc2[mt][1][r] + bd1;
                if (s != cur) {
                    atomicAdd(&out[(size_t)cur * DO + col0], sum0);
                    atomicAdd(&out[(size_t)cur * DO + col1], sum1);
                    cur = s; sum0 = v0; sum1 = v1;
                } else {
                    sum0 += v0; sum1 += v1;
                }
            }
        atomicAdd(&out[(size_t)cur * DO + col0], sum0);
        atomicAdd(&out[(size_t)cur * DO + col1], sum1);
    }
}

__global__ __launch_bounds__(128) void div_count(
    const int* __restrict__ senders, float* __restrict__ out)
{
    int n = blockIdx.x, d = threadIdx.x;
    int lo = 0, hi = E_TOT;
    while (lo < hi) { int m = (lo + hi) >> 1; if (senders[m] < n) lo = m + 1; else hi = m; }
    int s0 = lo;
    hi = E_TOT;
    while (lo < hi) { int m = (lo + hi) >> 1; if (senders[m] < n + 1) lo = m + 1; else hi = m; }
    int cnt = lo - s0;
    if (cnt > 1) out[(size_t)n * DO + d] *= (1.0f / (float)cnt);
}

extern "C" void kernel_launch(void* const* d_in, const int* in_sizes, int n_in,
                              void* d_out, int out_size, void* d_ws, size_t ws_size,
                              hipStream_t stream)
{
    const float* n_embed   = (const float*)d_in[0];
    const float* e_embed   = (const float*)d_in[1];
    const int*   senders   = (const int*)d_in[2];
    const int*   receivers = (const int*)d_in[3];
    const float* W1        = (const float*)d_in[4];
    const float* b1        = (const float*)d_in[5];
    const float* W2        = (const float*)d_in[6];
    const float* b2        = (const float*)d_in[7];
    float* out = (float*)d_out;

    unsigned short* Ps = (unsigned short*)d_ws;        // [NN][192] bf16
    unsigned short* Pr = Ps + (size_t)NN * DH;         // [NN][192] bf16

    prep<<<(FRAGS_TOT + NN * DO + 255) / 256, 256, 0, stream>>>(W1, W2, out);
    node_proj<<<dim3((NN + 63) / 64, 2), 256, 0, stream>>>(n_embed, b1, Ps);
    edge_mlp4<<<E_TOT / EB, 256, 0, stream>>>(
        e_embed, senders, receivers, Ps, Pr, b2, out);
    div_count<<<NN, 128, 0, stream>>>(senders, out);
}

// Round 6
// 105.001 us; speedup vs baseline: 1.2874x; 1.2874x over previous
//
#include <hip/hip_runtime.h>

#define E_TOT 320000
#define NN    10000
#define DN    128
#define DE    32
#define DH    192
#define DO    128
#define EB    64
#define SHS   196   // s_h row stride in ushorts (392 B = 49*8: b64-aligned, 4-way max)
#define SMS   67    // s_msgT row stride in f32 (268 B: bank step 3 -> ~2-way)

typedef __attribute__((ext_vector_type(8))) short bf16x8;
typedef __attribute__((ext_vector_type(4))) float f32x4;

// packed weight tables (rewritten every launch)
#define W1_FRAGS (8*12*64)    // node-part B-frags (node_proj)
#define E_FRAGS  (12*64)      // W1_edge^T A-frags (edge GEMM1)
#define W2_FRAGS (6*8*64)     // W2 B-frags
#define FRAGS_TOT (W1_FRAGS + E_FRAGS + W2_FRAGS)
__device__ __align__(16) unsigned short g_p1[W1_FRAGS * 8];
__device__ __align__(16) unsigned short g_e [E_FRAGS * 8];
__device__ __align__(16) unsigned short g_p2[W2_FRAGS * 8];

__device__ __forceinline__ unsigned short f2bf(float f) {
    union { float f; unsigned u; } v; v.f = f;
    return (unsigned short)((v.u + 0x7FFFu + ((v.u >> 16) & 1u)) >> 16);
}
__device__ __forceinline__ float bflo(unsigned u) {
    union { unsigned v; float f; } t; t.v = u << 16; return t.f;
}
__device__ __forceinline__ float bfhi(unsigned u) {
    union { unsigned v; float f; } t; t.v = u & 0xFFFF0000u; return t.f;
}
__device__ __forceinline__ float tanh_fast(float x) {
    float ex = __expf(x + x);
    return 1.0f - 2.0f * __builtin_amdgcn_rcpf(ex + 1.0f);
}
__device__ __forceinline__ unsigned cvt_pk_bf16(float lo, float hi) {
    unsigned r;
    asm("v_cvt_pk_bf16_f32 %0, %1, %2" : "=v"(r) : "v"(lo), "v"(hi));
    return r;
}

// ---------------------------------------------------------------------------
// prep: pack weight tables + zero output + per-node 1/count table
// ---------------------------------------------------------------------------
__global__ void prep(const float* __restrict__ W1, const float* __restrict__ W2,
                     const int* __restrict__ senders,
                     float* __restrict__ outz, float* __restrict__ invc)
{
    int f = blockIdx.x * 256 + threadIdx.x;
    unsigned short tmp[8];
    if (f < W1_FRAGS) {                       // node-part B-frags: rows 0..255 of W1
        int kk = f / (12 * 64), nt = (f >> 6) % 12, lane = f & 63;
        int r0 = kk * 32 + ((lane >> 4) << 3);
        int c  = nt * 16 + (lane & 15);
        #pragma unroll
        for (int i = 0; i < 8; ++i) tmp[i] = f2bf(W1[(r0 + i) * DH + c]);
        *(uint4*)(g_p1 + (size_t)f * 8) = *(const uint4*)tmp;
    } else if (f < W1_FRAGS + E_FRAGS) {      // W1_edge^T A-frags
        int f2 = f - W1_FRAGS;
        int mt = f2 >> 6, lane = f2 & 63;
        int k0 = ((lane >> 4) << 3);
        int hid = mt * 16 + (lane & 15);
        #pragma unroll
        for (int i = 0; i < 8; ++i) tmp[i] = f2bf(W1[(256 + k0 + i) * DH + hid]);
        *(uint4*)(g_e + (size_t)f2 * 8) = *(const uint4*)tmp;
    } else if (f < FRAGS_TOT) {               // W2 B-frags
        int f3 = f - W1_FRAGS - E_FRAGS;
        int kk = f3 / (8 * 64), nt = (f3 >> 6) % 8, lane = f3 & 63;
        int r0 = kk * 32 + ((lane >> 4) << 3);
        int c  = nt * 16 + (lane & 15);
        #pragma unroll
        for (int i = 0; i < 8; ++i) tmp[i] = f2bf(W2[(r0 + i) * DO + c]);
        *(uint4*)(g_p2 + (size_t)f3 * 8) = *(const uint4*)tmp;
    } else if (f < FRAGS_TOT + NN * DO) {
        outz[f - FRAGS_TOT] = 0.f;
    } else if (f < FRAGS_TOT + NN * DO + NN) {
        int n = f - FRAGS_TOT - NN * DO;
        int lo = 0, hi = E_TOT;
        while (lo < hi) { int m = (lo + hi) >> 1; if (senders[m] < n) lo = m + 1; else hi = m; }
        int s0 = lo;
        hi = E_TOT;
        while (lo < hi) { int m = (lo + hi) >> 1; if (senders[m] < n + 1) lo = m + 1; else hi = m; }
        int cnt = lo - s0;
        invc[n] = (cnt > 1) ? 1.0f / (float)cnt : 1.0f;
    }
}

// ---------------------------------------------------------------------------
// node projections, bf16 out: P_s = n@W1[0:128]+b1 (y=0), P_r = n@W1[128:256] (y=1)
// ---------------------------------------------------------------------------
__global__ __launch_bounds__(256) void node_proj(
    const float* __restrict__ n_embed, const float* __restrict__ b1,
    unsigned short* __restrict__ P)
{
    __shared__ __align__(16) unsigned short s_a[64][136];
    const int tid  = threadIdx.x;
    const int half = blockIdx.y;
    const int n0   = blockIdx.x * 64;

    #pragma unroll
    for (int it = 0; it < 8; ++it) {
        int idx = tid + it * 256;
        int row = idx >> 5, c = idx & 31;
        float4 v = make_float4(0.f, 0.f, 0.f, 0.f);
        if (n0 + row < NN) v = ((const float4*)(n_embed + (size_t)(n0 + row) * DN))[c];
        unsigned t0 = cvt_pk_bf16(v.x, v.y), t1 = cvt_pk_bf16(v.z, v.w);
        *(uint2*)&s_a[row][c * 4] = make_uint2(t0, t1);
    }
    __syncthreads();

    const int lane = tid & 63, w = tid >> 6;
    const int arow = lane & 15, akb = (lane >> 4) * 8, rbase = (lane >> 4) * 4;

    f32x4 acc[4][3];
    #pragma unroll
    for (int mt = 0; mt < 4; ++mt)
        #pragma unroll
        for (int j = 0; j < 3; ++j) acc[mt][j] = (f32x4){0.f, 0.f, 0.f, 0.f};

    for (int kk = 0; kk < 4; ++kk) {
        bf16x8 a[4], b[3];
        #pragma unroll
        for (int mt = 0; mt < 4; ++mt)
            a[mt] = *(const bf16x8*)&s_a[mt * 16 + arow][kk * 32 + akb];
        #pragma unroll
        for (int j = 0; j < 3; ++j)
            b[j] = *(const bf16x8*)(g_p1 + (((size_t)(kk + 4 * half) * 12 + (3 * w + j)) * 64 + lane) * 8);
        #pragma unroll
        for (int mt = 0; mt < 4; ++mt)
            #pragma unroll
            for (int j = 0; j < 3; ++j)
                acc[mt][j] = __builtin_amdgcn_mfma_f32_16x16x32_bf16(a[mt], b[j], acc[mt][j], 0, 0, 0);
    }

    unsigned short* Pout = P + (size_t)half * NN * DH;
    float bj[3];
    #pragma unroll
    for (int j = 0; j < 3; ++j) bj[j] = (half == 0) ? b1[48 * w + 16 * j + arow] : 0.f;
    #pragma unroll
    for (int mt = 0; mt < 4; ++mt)
        #pragma unroll
        for (int j = 0; j < 3; ++j)
            #pragma unroll
            for (int r = 0; r < 4; ++r) {
                int row = n0 + mt * 16 + rbase + r;
                if (row < NN)
                    Pout[(size_t)row * DH + 48 * w + 16 * j + arow] = f2bf(acc[mt][j][r] + bj[j]);
            }
}

// ---------------------------------------------------------------------------
// fused edge kernel:
//   barrier-free front half (direct global e-frags, early P gather),
//   transposed GEMM1 + tanh on accumulators -> s_h,
//   GEMM2 -> transposed spill s_msgT[col][edge] -> in-LDS column reduce
//   -> atomicAdd(out, run_sum * invc[node]).  3 barriers total.
// ---------------------------------------------------------------------------
__global__ __launch_bounds__(256, 4) void edge_mlp5(
    const float* __restrict__ e_embed,
    const int* __restrict__ senders, const int* __restrict__ receivers,
    const unsigned short* __restrict__ Ps, const unsigned short* __restrict__ Pr,
    const float* __restrict__ b2, const float* __restrict__ invc,
    float* __restrict__ out)
{
    __shared__ __align__(16) char s_u[128 * SMS * 4];      // 34304 B (union)
    __shared__ int s_send[EB];
    unsigned short (*s_h)[SHS] = (unsigned short(*)[SHS])s_u;  // [64][196] = 25088 B
    float          (*s_msgT)[SMS] = (float(*)[SMS])s_u;        // [128][67] = 34304 B

    const int tid  = threadIdx.x;
    const int nb8  = gridDim.x >> 3;
    const int e0   = (((blockIdx.x & 7) * nb8) + (blockIdx.x >> 3)) * EB;  // XCD swizzle
    const int lane = tid & 63, w = tid >> 6;
    const int arow = lane & 15, g = lane >> 4;

    // ---- phase 0: early per-lane loads (no LDS, no barrier) ----
    const int myedge = e0 + w * 16 + arow;
    const int sN = senders[myedge], rN = receivers[myedge];
    const unsigned short* psrow = Ps + (size_t)sN * DH;
    const unsigned short* prrow = Pr + (size_t)rN * DH;
    uint2 pv[12], qv[12];
    #pragma unroll
    for (int mt = 0; mt < 12; ++mt) {
        pv[mt] = *(const uint2*)(psrow + mt * 16 + g * 4);
        qv[mt] = *(const uint2*)(prrow + mt * 16 + g * 4);
    }
    // edge-feature B-frag direct from global (f32 -> bf16)
    union { bf16x8 v; unsigned u[4]; } bfr;
    {
        const float* erow = e_embed + (size_t)myedge * DE + g * 8;
        float4 ev0 = *(const float4*)erow;
        float4 ev1 = *(const float4*)(erow + 4);
        bfr.u[0] = cvt_pk_bf16(ev0.x, ev0.y);
        bfr.u[1] = cvt_pk_bf16(ev0.z, ev0.w);
        bfr.u[2] = cvt_pk_bf16(ev1.x, ev1.y);
        bfr.u[3] = cvt_pk_bf16(ev1.z, ev1.w);
    }
    if (tid < EB) s_send[tid] = senders[e0 + tid];

    // ---- phase 1: GEMM1^T (12 MFMAs) + P add + tanh -> s_h[edge][hid] ----
    #pragma unroll
    for (int mt = 0; mt < 12; ++mt) {
        bf16x8 af = *(const bf16x8*)(g_e + ((size_t)mt * 64 + lane) * 8);
        f32x4 z = (f32x4){0.f, 0.f, 0.f, 0.f};
        f32x4 acc = __builtin_amdgcn_mfma_f32_16x16x32_bf16(af, bfr.v, z, 0, 0, 0);
        float t0 = tanh_fast(acc[0] + bflo(pv[mt].x) + bflo(qv[mt].x));
        float t1 = tanh_fast(acc[1] + bfhi(pv[mt].x) + bfhi(qv[mt].x));
        float t2 = tanh_fast(acc[2] + bflo(pv[mt].y) + bflo(qv[mt].y));
        float t3 = tanh_fast(acc[3] + bfhi(pv[mt].y) + bfhi(qv[mt].y));
        *(uint2*)&s_h[w * 16 + arow][mt * 16 + g * 4] =
            make_uint2(cvt_pk_bf16(t0, t1), cvt_pk_bf16(t2, t3));
    }
    __syncthreads();

    // ---- phase 2: GEMM2  msg = h @ W2 ----
    f32x4 acc2[4][2];
    #pragma unroll
    for (int mt = 0; mt < 4; ++mt)
        #pragma unroll
        for (int j = 0; j < 2; ++j) acc2[mt][j] = (f32x4){0.f, 0.f, 0.f, 0.f};

    #pragma unroll
    for (int kk = 0; kk < 6; ++kk) {
        union { bf16x8 v; uint2 p[2]; } a[4];
        bf16x8 b[2];
        #pragma unroll
        for (int mt = 0; mt < 4; ++mt) {
            const unsigned short* hp = &s_h[mt * 16 + arow][kk * 32 + g * 8];
            a[mt].p[0] = *(const uint2*)hp;
            a[mt].p[1] = *(const uint2*)(hp + 4);
        }
        #pragma unroll
        for (int j = 0; j < 2; ++j)
            b[j] = *(const bf16x8*)(g_p2 + (((size_t)kk * 8 + (2 * w + j)) * 64 + lane) * 8);
        #pragma unroll
        for (int mt = 0; mt < 4; ++mt)
            #pragma unroll
            for (int j = 0; j < 2; ++j)
                acc2[mt][j] = __builtin_amdgcn_mfma_f32_16x16x32_bf16(a[mt].v, b[j], acc2[mt][j], 0, 0, 0);
    }
    __syncthreads();   // all s_h reads done before s_msgT overwrites the union

    // ---- phase 3: transposed spill  s_msgT[col][edge] ----
    {
        const float bd0 = b2[32 * w + arow], bd1 = b2[32 * w + 16 + arow];
        #pragma unroll
        for (int mt = 0; mt < 4; ++mt)
            #pragma unroll
            for (int r = 0; r < 4; ++r) {
                int e = mt * 16 + g * 4 + r;
                s_msgT[32 * w + arow][e]      = acc2[mt][0][r] + bd0;
                s_msgT[32 * w + 16 + arow][e] = acc2[mt][1][r] + bd1;
            }
    }
    __syncthreads();

    // ---- phase 4: per-column segment reduce (sorted senders), scaled flush ----
    {
        const int c  = tid & 127;
        const int r0 = (tid >> 7) * 32;
        float sum = 0.f;
        int cur = s_send[r0];
        for (int e = r0; e < r0 + 32; ++e) {
            sum += s_msgT[c][e];
            int nxt = (e + 1 < r0 + 32) ? s_send[e + 1] : -1;
            if (nxt != cur) {
                atomicAdd(&out[(size_t)cur * DO + c], sum * invc[cur]);
                sum = 0.f;
                cur = nxt;
            }
        }
    }
}

extern "C" void kernel_launch(void* const* d_in, const int* in_sizes, int n_in,
                              void* d_out, int out_size, void* d_ws, size_t ws_size,
                              hipStream_t stream)
{
    const float* n_embed   = (const float*)d_in[0];
    const float* e_embed   = (const float*)d_in[1];
    const int*   senders   = (const int*)d_in[2];
    const int*   receivers = (const int*)d_in[3];
    const float* W1        = (const float*)d_in[4];
    const float* b1        = (const float*)d_in[5];
    const float* W2        = (const float*)d_in[6];
    const float* b2        = (const float*)d_in[7];
    float* out = (float*)d_out;

    unsigned short* Ps = (unsigned short*)d_ws;        // [NN][192] bf16
    unsigned short* Pr = Ps + (size_t)NN * DH;         // [NN][192] bf16
    float*          invc = (float*)(Pr + (size_t)NN * DH);  // [NN] f32

    const int prep_items = FRAGS_TOT + NN * DO + NN;
    prep<<<(prep_items + 255) / 256, 256, 0, stream>>>(W1, W2, senders, out, invc);
    node_proj<<<dim3((NN + 63) / 64, 2), 256, 0, stream>>>(n_embed, b1, Ps);
    edge_mlp5<<<E_TOT / EB, 256, 0, stream>>>(
        e_embed, senders, receivers, Ps, Pr, b2, invc, out);
}

// Round 9
// 100.424 us; speedup vs baseline: 1.3461x; 1.0456x over previous
//
#include <hip/hip_runtime.h>

#define E_TOT 320000
#define NN    10000
#define DN    128
#define DE    32
#define DH    192
#define DO    128
#define EB    64
#define SHS   196   // s_h row stride in ushorts (392 B)
#define SMT   68    // s_msgT row stride in ushorts (136 B, 8B-aligned)

typedef __attribute__((ext_vector_type(8))) short bf16x8;
typedef __attribute__((ext_vector_type(4))) float f32x4;

// packed weight tables (rewritten every launch)
#define W1_FRAGS (8*12*64)    // node-part B-frags (node_proj)
#define E_FRAGS  (12*64)      // W1_edge^T A-frags (edge GEMM1)
#define W2_FRAGS (6*8*64)     // W2 B-frags
#define FRAGS_TOT (W1_FRAGS + E_FRAGS + W2_FRAGS)
__device__ __align__(16) unsigned short g_p1[W1_FRAGS * 8];
__device__ __align__(16) unsigned short g_e [E_FRAGS * 8];
__device__ __align__(16) unsigned short g_p2[W2_FRAGS * 8];

__device__ __forceinline__ unsigned short f2bf(float f) {
    union { float f; unsigned u; } v; v.f = f;
    return (unsigned short)((v.u + 0x7FFFu + ((v.u >> 16) & 1u)) >> 16);
}
__device__ __forceinline__ float bflo(unsigned u) {
    union { unsigned v; float f; } t; t.v = u << 16; return t.f;
}
__device__ __forceinline__ float bfhi(unsigned u) {
    union { unsigned v; float f; } t; t.v = u & 0xFFFF0000u; return t.f;
}
__device__ __forceinline__ float bf2f(unsigned short s) {
    union { unsigned v; float f; } t; t.v = (unsigned)s << 16; return t.f;
}
__device__ __forceinline__ float tanh_fast(float x) {
    float ex = __expf(x + x);
    return 1.0f - 2.0f * __builtin_amdgcn_rcpf(ex + 1.0f);
}
__device__ __forceinline__ unsigned cvt_pk_bf16(float lo, float hi) {
    unsigned r;
    asm("v_cvt_pk_bf16_f32 %0, %1, %2" : "=v"(r) : "v"(lo), "v"(hi));
    return r;
}

// ---------------------------------------------------------------------------
// prep: pack weight tables + zero output + per-node 1/count table  (= R5's)
// ---------------------------------------------------------------------------
__global__ void prep(const float* __restrict__ W1, const float* __restrict__ W2,
                     const int* __restrict__ senders,
                     float* __restrict__ outz, float* __restrict__ invc)
{
    int f = blockIdx.x * 256 + threadIdx.x;
    unsigned short tmp[8];
    if (f < W1_FRAGS) {                       // node-part B-frags: rows 0..255 of W1
        int kk = f / (12 * 64), nt = (f >> 6) % 12, lane = f & 63;
        int r0 = kk * 32 + ((lane >> 4) << 3);
        int c  = nt * 16 + (lane & 15);
        #pragma unroll
        for (int i = 0; i < 8; ++i) tmp[i] = f2bf(W1[(r0 + i) * DH + c]);
        *(uint4*)(g_p1 + (size_t)f * 8) = *(const uint4*)tmp;
    } else if (f < W1_FRAGS + E_FRAGS) {      // W1_edge^T A-frags
        int f2 = f - W1_FRAGS;
        int mt = f2 >> 6, lane = f2 & 63;
        int k0 = ((lane >> 4) << 3);
        int hid = mt * 16 + (lane & 15);
        #pragma unroll
        for (int i = 0; i < 8; ++i) tmp[i] = f2bf(W1[(256 + k0 + i) * DH + hid]);
        *(uint4*)(g_e + (size_t)f2 * 8) = *(const uint4*)tmp;
    } else if (f < FRAGS_TOT) {               // W2 B-frags
        int f3 = f - W1_FRAGS - E_FRAGS;
        int kk = f3 / (8 * 64), nt = (f3 >> 6) % 8, lane = f3 & 63;
        int r0 = kk * 32 + ((lane >> 4) << 3);
        int c  = nt * 16 + (lane & 15);
        #pragma unroll
        for (int i = 0; i < 8; ++i) tmp[i] = f2bf(W2[(r0 + i) * DO + c]);
        *(uint4*)(g_p2 + (size_t)f3 * 8) = *(const uint4*)tmp;
    } else if (f < FRAGS_TOT + NN * DO) {
        outz[f - FRAGS_TOT] = 0.f;
    } else if (f < FRAGS_TOT + NN * DO + NN) {
        int n = f - FRAGS_TOT - NN * DO;
        int lo = 0, hi = E_TOT;
        while (lo < hi) { int m = (lo + hi) >> 1; if (senders[m] < n) lo = m + 1; else hi = m; }
        int s0 = lo;
        hi = E_TOT;
        while (lo < hi) { int m = (lo + hi) >> 1; if (senders[m] < n + 1) lo = m + 1; else hi = m; }
        int cnt = lo - s0;
        invc[n] = (cnt > 1) ? 1.0f / (float)cnt : 1.0f;
    }
}

// ---------------------------------------------------------------------------
// node projections (= R5's, verbatim)
// ---------------------------------------------------------------------------
__global__ __launch_bounds__(256) void node_proj(
    const float* __restrict__ n_embed, const float* __restrict__ b1,
    unsigned short* __restrict__ P)
{
    __shared__ __align__(16) unsigned short s_a[64][136];
    const int tid  = threadIdx.x;
    const int half = blockIdx.y;
    const int n0   = blockIdx.x * 64;

    #pragma unroll
    for (int it = 0; it < 8; ++it) {
        int idx = tid + it * 256;
        int row = idx >> 5, c = idx & 31;
        float4 v = make_float4(0.f, 0.f, 0.f, 0.f);
        if (n0 + row < NN) v = ((const float4*)(n_embed + (size_t)(n0 + row) * DN))[c];
        unsigned t0 = cvt_pk_bf16(v.x, v.y), t1 = cvt_pk_bf16(v.z, v.w);
        *(uint2*)&s_a[row][c * 4] = make_uint2(t0, t1);
    }
    __syncthreads();

    const int lane = tid & 63, w = tid >> 6;
    const int arow = lane & 15, akb = (lane >> 4) * 8, rbase = (lane >> 4) * 4;

    f32x4 acc[4][3];
    #pragma unroll
    for (int mt = 0; mt < 4; ++mt)
        #pragma unroll
        for (int j = 0; j < 3; ++j) acc[mt][j] = (f32x4){0.f, 0.f, 0.f, 0.f};

    for (int kk = 0; kk < 4; ++kk) {
        bf16x8 a[4], b[3];
        #pragma unroll
        for (int mt = 0; mt < 4; ++mt)
            a[mt] = *(const bf16x8*)&s_a[mt * 16 + arow][kk * 32 + akb];
        #pragma unroll
        for (int j = 0; j < 3; ++j)
            b[j] = *(const bf16x8*)(g_p1 + (((size_t)(kk + 4 * half) * 12 + (3 * w + j)) * 64 + lane) * 8);
        #pragma unroll
        for (int mt = 0; mt < 4; ++mt)
            #pragma unroll
            for (int j = 0; j < 3; ++j)
                acc[mt][j] = __builtin_amdgcn_mfma_f32_16x16x32_bf16(a[mt], b[j], acc[mt][j], 0, 0, 0);
    }

    unsigned short* Pout = P + (size_t)half * NN * DH;
    float bj[3];
    #pragma unroll
    for (int j = 0; j < 3; ++j) bj[j] = (half == 0) ? b1[48 * w + 16 * j + arow] : 0.f;
    #pragma unroll
    for (int mt = 0; mt < 4; ++mt)
        #pragma unroll
        for (int j = 0; j < 3; ++j)
            #pragma unroll
            for (int r = 0; r < 4; ++r) {
                int row = n0 + mt * 16 + rbase + r;
                if (row < NN)
                    Pout[(size_t)row * DH + 48 * w + 16 * j + arow] = f2bf(acc[mt][j][r] + bj[j]);
            }
}

// ---------------------------------------------------------------------------
// fused edge kernel = R5's edge_mlp5 with exactly ONE delta: the msg spill is
// bf16 (bias added via VALU before cvt_pk, flush logic unchanged + bf2f).
// LDS union 34304 -> 25088 B => 6 blocks/CU by LDS (was 4).
// ---------------------------------------------------------------------------
__global__ __launch_bounds__(256, 4) void edge_mlp8(
    const float* __restrict__ e_embed,
    const int* __restrict__ senders, const int* __restrict__ receivers,
    const unsigned short* __restrict__ Ps, const unsigned short* __restrict__ Pr,
    const float* __restrict__ b2, const float* __restrict__ invc,
    float* __restrict__ out)
{
    __shared__ __align__(16) char s_u[64 * SHS * 2];       // 25088 B (union)
    __shared__ int s_send[EB];
    unsigned short (*s_h)[SHS]    = (unsigned short(*)[SHS])s_u;  // [64][196] = 25088 B
    unsigned short (*s_msgT)[SMT] = (unsigned short(*)[SMT])s_u;  // [128][68] = 17408 B

    const int tid  = threadIdx.x;
    const int nb8  = gridDim.x >> 3;
    const int e0   = (((blockIdx.x & 7) * nb8) + (blockIdx.x >> 3)) * EB;  // XCD swizzle
    const int lane = tid & 63, w = tid >> 6;
    const int arow = lane & 15, g = lane >> 4;

    // ---- phase 0: early per-lane loads (no LDS deps, no barrier) ----
    const int myedge = e0 + w * 16 + arow;
    const int sN = senders[myedge], rN = receivers[myedge];
    const unsigned short* psrow = Ps + (size_t)sN * DH;
    const unsigned short* prrow = Pr + (size_t)rN * DH;
    uint2 pv[12], qv[12];
    #pragma unroll
    for (int mt = 0; mt < 12; ++mt) {
        pv[mt] = *(const uint2*)(psrow + mt * 16 + g * 4);
        qv[mt] = *(const uint2*)(prrow + mt * 16 + g * 4);
    }
    union { bf16x8 v; unsigned u[4]; } bfr;
    {
        const float* erow = e_embed + (size_t)myedge * DE + g * 8;
        float4 ev0 = *(const float4*)erow;
        float4 ev1 = *(const float4*)(erow + 4);
        bfr.u[0] = cvt_pk_bf16(ev0.x, ev0.y);
        bfr.u[1] = cvt_pk_bf16(ev0.z, ev0.w);
        bfr.u[2] = cvt_pk_bf16(ev1.x, ev1.y);
        bfr.u[3] = cvt_pk_bf16(ev1.z, ev1.w);
    }
    if (tid < EB) s_send[tid] = senders[e0 + tid];

    // ---- phase 1: GEMM1^T (12 MFMAs) + P add + tanh -> s_h[edge][hid] ----
    #pragma unroll
    for (int mt = 0; mt < 12; ++mt) {
        bf16x8 af = *(const bf16x8*)(g_e + ((size_t)mt * 64 + lane) * 8);
        f32x4 z = (f32x4){0.f, 0.f, 0.f, 0.f};
        f32x4 acc = __builtin_amdgcn_mfma_f32_16x16x32_bf16(af, bfr.v, z, 0, 0, 0);
        float t0 = tanh_fast(acc[0] + bflo(pv[mt].x) + bflo(qv[mt].x));
        float t1 = tanh_fast(acc[1] + bfhi(pv[mt].x) + bfhi(qv[mt].x));
        float t2 = tanh_fast(acc[2] + bflo(pv[mt].y) + bflo(qv[mt].y));
        float t3 = tanh_fast(acc[3] + bfhi(pv[mt].y) + bfhi(qv[mt].y));
        *(uint2*)&s_h[w * 16 + arow][mt * 16 + g * 4] =
            make_uint2(cvt_pk_bf16(t0, t1), cvt_pk_bf16(t2, t3));
    }
    __syncthreads();

    // ---- phase 2: GEMM2  msg = h @ W2 ----
    f32x4 acc2[4][2];
    #pragma unroll
    for (int mt = 0; mt < 4; ++mt)
        #pragma unroll
        for (int j = 0; j < 2; ++j) acc2[mt][j] = (f32x4){0.f, 0.f, 0.f, 0.f};

    #pragma unroll
    for (int kk = 0; kk < 6; ++kk) {
        union { bf16x8 v; uint2 p[2]; } a[4];
        bf16x8 b[2];
        #pragma unroll
        for (int mt = 0; mt < 4; ++mt) {
            const unsigned short* hp = &s_h[mt * 16 + arow][kk * 32 + g * 8];
            a[mt].p[0] = *(const uint2*)hp;
            a[mt].p[1] = *(const uint2*)(hp + 4);
        }
        #pragma unroll
        for (int j = 0; j < 2; ++j)
            b[j] = *(const bf16x8*)(g_p2 + (((size_t)kk * 8 + (2 * w + j)) * 64 + lane) * 8);
        #pragma unroll
        for (int mt = 0; mt < 4; ++mt)
            #pragma unroll
            for (int j = 0; j < 2; ++j)
                acc2[mt][j] = __builtin_amdgcn_mfma_f32_16x16x32_bf16(a[mt].v, b[j], acc2[mt][j], 0, 0, 0);
    }
    __syncthreads();   // all s_h reads done before s_msgT overwrites the union

    // ---- phase 3: bf16 transposed spill  s_msgT[col][edge], bias added first ----
    {
        const float bd0 = b2[32 * w + arow], bd1 = b2[32 * w + 16 + arow];
        #pragma unroll
        for (int mt = 0; mt < 4; ++mt) {
            float v0 = acc2[mt][0][0] + bd0, v1 = acc2[mt][0][1] + bd0;
            float v2 = acc2[mt][0][2] + bd0, v3 = acc2[mt][0][3] + bd0;
            *(uint2*)&s_msgT[32 * w + arow][mt * 16 + g * 4] =
                make_uint2(cvt_pk_bf16(v0, v1), cvt_pk_bf16(v2, v3));
            float u0 = acc2[mt][1][0] + bd1, u1 = acc2[mt][1][1] + bd1;
            float u2 = acc2[mt][1][2] + bd1, u3 = acc2[mt][1][3] + bd1;
            *(uint2*)&s_msgT[32 * w + 16 + arow][mt * 16 + g * 4] =
                make_uint2(cvt_pk_bf16(u0, u1), cvt_pk_bf16(u2, u3));
        }
    }
    __syncthreads();

    // ---- phase 4: per-column segment reduce (sorted senders), scaled flush ----
    {
        const int c  = tid & 127;
        const int r0 = (tid >> 7) * 32;
        float sum = 0.f;
        int cur = s_send[r0];
        for (int e = r0; e < r0 + 32; ++e) {
            sum += bf2f(s_msgT[c][e]);
            int nxt = (e + 1 < r0 + 32) ? s_send[e + 1] : -1;
            if (nxt != cur) {
                atomicAdd(&out[(size_t)cur * DO + c], sum * invc[cur]);
                sum = 0.f;
                cur = nxt;
            }
        }
    }
}

extern "C" void kernel_launch(void* const* d_in, const int* in_sizes, int n_in,
                              void* d_out, int out_size, void* d_ws, size_t ws_size,
                              hipStream_t stream)
{
    const float* n_embed   = (const float*)d_in[0];
    const float* e_embed   = (const float*)d_in[1];
    const int*   senders   = (const int*)d_in[2];
    const int*   receivers = (const int*)d_in[3];
    const float* W1        = (const float*)d_in[4];
    const float* b1        = (const float*)d_in[5];
    const float* W2        = (const float*)d_in[6];
    const float* b2        = (const float*)d_in[7];
    float* out = (float*)d_out;

    unsigned short* Ps = (unsigned short*)d_ws;             // [NN][192] bf16
    unsigned short* Pr = Ps + (size_t)NN * DH;              // [NN][192] bf16
    float*          invc = (float*)(Pr + (size_t)NN * DH);  // [NN] f32

    const int prep_items = FRAGS_TOT + NN * DO + NN;
    prep<<<(prep_items + 255) / 256, 256, 0, stream>>>(W1, W2, senders, out, invc);
    node_proj<<<dim3((NN + 63) / 64, 2), 256, 0, stream>>>(n_embed, b1, Ps);
    edge_mlp8<<<E_TOT / EB, 256, 0, stream>>>(
        e_embed, senders, receivers, Ps, Pr, b2, invc, out);
}

// Round 10
// 85.318 us; speedup vs baseline: 1.5844x; 1.1771x over previous
//
#include <hip/hip_runtime.h>

#define E_TOT 320000
#define NN    10000
#define DN    128
#define DE    32
#define DH    192
#define DO    128
#define EB    64
#define SHS   196   // s_h row stride in ushorts (392 B)
#define SMT   68    // s_msgT row stride in ushorts (136 B, 8B-aligned)

typedef __attribute__((ext_vector_type(8))) short bf16x8;
typedef __attribute__((ext_vector_type(4))) float f32x4;

// packed weight tables (rewritten every launch)
#define W1_FRAGS (8*12*64)    // node-part B-frags (node_proj)
#define E_FRAGS  (12*64)      // W1_edge^T A-frags (edge GEMM1)
#define W2_FRAGS (6*8*64)     // W2 B-frags
#define FRAGS_TOT (W1_FRAGS + E_FRAGS + W2_FRAGS)
__device__ __align__(16) unsigned short g_p1[W1_FRAGS * 8];
__device__ __align__(16) unsigned short g_e [E_FRAGS * 8];
__device__ __align__(16) unsigned short g_p2[W2_FRAGS * 8];

__device__ __forceinline__ unsigned short f2bf(float f) {
    union { float f; unsigned u; } v; v.f = f;
    return (unsigned short)((v.u + 0x7FFFu + ((v.u >> 16) & 1u)) >> 16);
}
__device__ __forceinline__ float bflo(unsigned u) {
    union { unsigned v; float f; } t; t.v = u << 16; return t.f;
}
__device__ __forceinline__ float bfhi(unsigned u) {
    union { unsigned v; float f; } t; t.v = u & 0xFFFF0000u; return t.f;
}
__device__ __forceinline__ float bf2f(unsigned short s) {
    union { unsigned v; float f; } t; t.v = (unsigned)s << 16; return t.f;
}
__device__ __forceinline__ float tanh_fast(float x) {
    float ex = __expf(x + x);
    return 1.0f - 2.0f * __builtin_amdgcn_rcpf(ex + 1.0f);
}
__device__ __forceinline__ unsigned cvt_pk_bf16(float lo, float hi) {
    unsigned r;
    asm("v_cvt_pk_bf16_f32 %0, %1, %2" : "=v"(r) : "v"(lo), "v"(hi));
    return r;
}

// ---------------------------------------------------------------------------
// prep: pack weight tables + zero output + per-node 1/count table  (= R8's)
// ---------------------------------------------------------------------------
__global__ void prep(const float* __restrict__ W1, const float* __restrict__ W2,
                     const int* __restrict__ senders,
                     float* __restrict__ outz, float* __restrict__ invc)
{
    int f = blockIdx.x * 256 + threadIdx.x;
    unsigned short tmp[8];
    if (f < W1_FRAGS) {                       // node-part B-frags: rows 0..255 of W1
        int kk = f / (12 * 64), nt = (f >> 6) % 12, lane = f & 63;
        int r0 = kk * 32 + ((lane >> 4) << 3);
        int c  = nt * 16 + (lane & 15);
        #pragma unroll
        for (int i = 0; i < 8; ++i) tmp[i] = f2bf(W1[(r0 + i) * DH + c]);
        *(uint4*)(g_p1 + (size_t)f * 8) = *(const uint4*)tmp;
    } else if (f < W1_FRAGS + E_FRAGS) {      // W1_edge^T A-frags
        int f2 = f - W1_FRAGS;
        int mt = f2 >> 6, lane = f2 & 63;
        int k0 = ((lane >> 4) << 3);
        int hid = mt * 16 + (lane & 15);
        #pragma unroll
        for (int i = 0; i < 8; ++i) tmp[i] = f2bf(W1[(256 + k0 + i) * DH + hid]);
        *(uint4*)(g_e + (size_t)f2 * 8) = *(const uint4*)tmp;
    } else if (f < FRAGS_TOT) {               // W2 B-frags
        int f3 = f - W1_FRAGS - E_FRAGS;
        int kk = f3 / (8 * 64), nt = (f3 >> 6) % 8, lane = f3 & 63;
        int r0 = kk * 32 + ((lane >> 4) << 3);
        int c  = nt * 16 + (lane & 15);
        #pragma unroll
        for (int i = 0; i < 8; ++i) tmp[i] = f2bf(W2[(r0 + i) * DO + c]);
        *(uint4*)(g_p2 + (size_t)f3 * 8) = *(const uint4*)tmp;
    } else if (f < FRAGS_TOT + NN * DO) {
        outz[f - FRAGS_TOT] = 0.f;
    } else if (f < FRAGS_TOT + NN * DO + NN) {
        int n = f - FRAGS_TOT - NN * DO;
        int lo = 0, hi = E_TOT;
        while (lo < hi) { int m = (lo + hi) >> 1; if (senders[m] < n) lo = m + 1; else hi = m; }
        int s0 = lo;
        hi = E_TOT;
        while (lo < hi) { int m = (lo + hi) >> 1; if (senders[m] < n + 1) lo = m + 1; else hi = m; }
        int cnt = lo - s0;
        invc[n] = (cnt > 1) ? 1.0f / (float)cnt : 1.0f;
    }
}

// ---------------------------------------------------------------------------
// node projections (= R8's except the P store layout):
//   P'[n][g][mt][i]  (g=0..3, mt=0..11, i=0..3), i.e. addr = (n*4+g)*48 + mt*4 + i
//   original col = mt*16 + g*4 + i.  Lane-contiguous 96B per (n,g).
// ---------------------------------------------------------------------------
__global__ __launch_bounds__(256) void node_proj(
    const float* __restrict__ n_embed, const float* __restrict__ b1,
    unsigned short* __restrict__ P)
{
    __shared__ __align__(16) unsigned short s_a[64][136];
    const int tid  = threadIdx.x;
    const int half = blockIdx.y;
    const int n0   = blockIdx.x * 64;

    #pragma unroll
    for (int it = 0; it < 8; ++it) {
        int idx = tid + it * 256;
        int row = idx >> 5, c = idx & 31;
        float4 v = make_float4(0.f, 0.f, 0.f, 0.f);
        if (n0 + row < NN) v = ((const float4*)(n_embed + (size_t)(n0 + row) * DN))[c];
        unsigned t0 = cvt_pk_bf16(v.x, v.y), t1 = cvt_pk_bf16(v.z, v.w);
        *(uint2*)&s_a[row][c * 4] = make_uint2(t0, t1);
    }
    __syncthreads();

    const int lane = tid & 63, w = tid >> 6;
    const int arow = lane & 15, akb = (lane >> 4) * 8, rbase = (lane >> 4) * 4;

    f32x4 acc[4][3];
    #pragma unroll
    for (int mt = 0; mt < 4; ++mt)
        #pragma unroll
        for (int j = 0; j < 3; ++j) acc[mt][j] = (f32x4){0.f, 0.f, 0.f, 0.f};

    for (int kk = 0; kk < 4; ++kk) {
        bf16x8 a[4], b[3];
        #pragma unroll
        for (int mt = 0; mt < 4; ++mt)
            a[mt] = *(const bf16x8*)&s_a[mt * 16 + arow][kk * 32 + akb];
        #pragma unroll
        for (int j = 0; j < 3; ++j)
            b[j] = *(const bf16x8*)(g_p1 + (((size_t)(kk + 4 * half) * 12 + (3 * w + j)) * 64 + lane) * 8);
        #pragma unroll
        for (int mt = 0; mt < 4; ++mt)
            #pragma unroll
            for (int j = 0; j < 3; ++j)
                acc[mt][j] = __builtin_amdgcn_mfma_f32_16x16x32_bf16(a[mt], b[j], acc[mt][j], 0, 0, 0);
    }

    unsigned short* Pout = P + (size_t)half * NN * DH;
    float bj[3];
    #pragma unroll
    for (int j = 0; j < 3; ++j) bj[j] = (half == 0) ? b1[48 * w + 16 * j + arow] : 0.f;
    const int gq = arow >> 2, ii = arow & 3;   // col = (3w+j)*16 + gq*4 + ii
    #pragma unroll
    for (int mt = 0; mt < 4; ++mt)
        #pragma unroll
        for (int j = 0; j < 3; ++j)
            #pragma unroll
            for (int r = 0; r < 4; ++r) {
                int row = n0 + mt * 16 + rbase + r;
                if (row < NN)
                    Pout[((size_t)row * 4 + gq) * 48 + (3 * w + j) * 4 + ii] =
                        f2bf(acc[mt][j][r] + bj[j]);
            }
}

// ---------------------------------------------------------------------------
// fused edge kernel = R8's edge_mlp8 with two deltas:
//   (1) P gather is 6+6 uint4 loads from the lane-contiguous P' layout
//       (96 contiguous bytes per table per lane) instead of 12+12 uint2;
//   (2) phase-4 reduce preloads its 32 LDS values into registers.
// ---------------------------------------------------------------------------
__global__ __launch_bounds__(256, 4) void edge_mlp9(
    const float* __restrict__ e_embed,
    const int* __restrict__ senders, const int* __restrict__ receivers,
    const unsigned short* __restrict__ Ps, const unsigned short* __restrict__ Pr,
    const float* __restrict__ b2, const float* __restrict__ invc,
    float* __restrict__ out)
{
    __shared__ __align__(16) char s_u[64 * SHS * 2];       // 25088 B (union)
    __shared__ int s_send[EB];
    unsigned short (*s_h)[SHS]    = (unsigned short(*)[SHS])s_u;  // [64][196]
    unsigned short (*s_msgT)[SMT] = (unsigned short(*)[SMT])s_u;  // [128][68]

    const int tid  = threadIdx.x;
    const int nb8  = gridDim.x >> 3;
    const int e0   = (((blockIdx.x & 7) * nb8) + (blockIdx.x >> 3)) * EB;  // XCD swizzle
    const int lane = tid & 63, w = tid >> 6;
    const int arow = lane & 15, g = lane >> 4;

    // ---- phase 0: early per-lane loads (wide, contiguous per lane) ----
    const int myedge = e0 + w * 16 + arow;
    const int sN = senders[myedge], rN = receivers[myedge];
    const unsigned short* psbase = Ps + ((size_t)sN * 4 + g) * 48;
    const unsigned short* prbase = Pr + ((size_t)rN * 4 + g) * 48;
    uint4 psq[6], prq[6];
    #pragma unroll
    for (int j = 0; j < 6; ++j) {
        psq[j] = *(const uint4*)(psbase + j * 8);
        prq[j] = *(const uint4*)(prbase + j * 8);
    }
    union { bf16x8 v; unsigned u[4]; } bfr;
    {
        const float* erow = e_embed + (size_t)myedge * DE + g * 8;
        float4 ev0 = *(const float4*)erow;
        float4 ev1 = *(const float4*)(erow + 4);
        bfr.u[0] = cvt_pk_bf16(ev0.x, ev0.y);
        bfr.u[1] = cvt_pk_bf16(ev0.z, ev0.w);
        bfr.u[2] = cvt_pk_bf16(ev1.x, ev1.y);
        bfr.u[3] = cvt_pk_bf16(ev1.z, ev1.w);
    }
    if (tid < EB) s_send[tid] = senders[e0 + tid];

    // ---- phase 1: GEMM1^T (12 MFMAs) + P add + tanh -> s_h[edge][hid] ----
    #pragma unroll
    for (int mt = 0; mt < 12; ++mt) {
        unsigned px, py, qx, qy;
        if ((mt & 1) == 0) {
            px = psq[mt >> 1].x; py = psq[mt >> 1].y;
            qx = prq[mt >> 1].x; qy = prq[mt >> 1].y;
        } else {
            px = psq[mt >> 1].z; py = psq[mt >> 1].w;
            qx = prq[mt >> 1].z; qy = prq[mt >> 1].w;
        }
        bf16x8 af = *(const bf16x8*)(g_e + ((size_t)mt * 64 + lane) * 8);
        f32x4 z = (f32x4){0.f, 0.f, 0.f, 0.f};
        f32x4 acc = __builtin_amdgcn_mfma_f32_16x16x32_bf16(af, bfr.v, z, 0, 0, 0);
        float t0 = tanh_fast(acc[0] + bflo(px) + bflo(qx));
        float t1 = tanh_fast(acc[1] + bfhi(px) + bfhi(qx));
        float t2 = tanh_fast(acc[2] + bflo(py) + bflo(qy));
        float t3 = tanh_fast(acc[3] + bfhi(py) + bfhi(qy));
        *(uint2*)&s_h[w * 16 + arow][mt * 16 + g * 4] =
            make_uint2(cvt_pk_bf16(t0, t1), cvt_pk_bf16(t2, t3));
    }
    __syncthreads();

    // ---- phase 2: GEMM2  msg = h @ W2 ----
    f32x4 acc2[4][2];
    #pragma unroll
    for (int mt = 0; mt < 4; ++mt)
        #pragma unroll
        for (int j = 0; j < 2; ++j) acc2[mt][j] = (f32x4){0.f, 0.f, 0.f, 0.f};

    #pragma unroll
    for (int kk = 0; kk < 6; ++kk) {
        union { bf16x8 v; uint2 p[2]; } a[4];
        bf16x8 b[2];
        #pragma unroll
        for (int mt = 0; mt < 4; ++mt) {
            const unsigned short* hp = &s_h[mt * 16 + arow][kk * 32 + g * 8];
            a[mt].p[0] = *(const uint2*)hp;
            a[mt].p[1] = *(const uint2*)(hp + 4);
        }
        #pragma unroll
        for (int j = 0; j < 2; ++j)
            b[j] = *(const bf16x8*)(g_p2 + (((size_t)kk * 8 + (2 * w + j)) * 64 + lane) * 8);
        #pragma unroll
        for (int mt = 0; mt < 4; ++mt)
            #pragma unroll
            for (int j = 0; j < 2; ++j)
                acc2[mt][j] = __builtin_amdgcn_mfma_f32_16x16x32_bf16(a[mt].v, b[j], acc2[mt][j], 0, 0, 0);
    }
    __syncthreads();   // all s_h reads done before s_msgT overwrites the union

    // ---- phase 3: bf16 transposed spill  s_msgT[col][edge], bias added first ----
    {
        const float bd0 = b2[32 * w + arow], bd1 = b2[32 * w + 16 + arow];
        #pragma unroll
        for (int mt = 0; mt < 4; ++mt) {
            float v0 = acc2[mt][0][0] + bd0, v1 = acc2[mt][0][1] + bd0;
            float v2 = acc2[mt][0][2] + bd0, v3 = acc2[mt][0][3] + bd0;
            *(uint2*)&s_msgT[32 * w + arow][mt * 16 + g * 4] =
                make_uint2(cvt_pk_bf16(v0, v1), cvt_pk_bf16(v2, v3));
            float u0 = acc2[mt][1][0] + bd1, u1 = acc2[mt][1][1] + bd1;
            float u2 = acc2[mt][1][2] + bd1, u3 = acc2[mt][1][3] + bd1;
            *(uint2*)&s_msgT[32 * w + 16 + arow][mt * 16 + g * 4] =
                make_uint2(cvt_pk_bf16(u0, u1), cvt_pk_bf16(u2, u3));
        }
    }
    __syncthreads();

    // ---- phase 4: per-column segment reduce (sorted senders), scaled flush ----
    {
        const int c  = tid & 127;
        const int r0 = (tid >> 7) * 32;
        float vals[32];
        #pragma unroll
        for (int e = 0; e < 32; ++e) vals[e] = bf2f(s_msgT[c][r0 + e]);
        float sum = 0.f;
        int cur = s_send[r0];
        #pragma unroll
        for (int e = 0; e < 32; ++e) {
            sum += vals[e];
            int nxt = (e + 1 < 32) ? s_send[r0 + e + 1] : -1;
            if (nxt != cur) {
                atomicAdd(&out[(size_t)cur * DO + c], sum * invc[cur]);
                sum = 0.f;
                cur = nxt;
            }
        }
    }
}

extern "C" void kernel_launch(void* const* d_in, const int* in_sizes, int n_in,
                              void* d_out, int out_size, void* d_ws, size_t ws_size,
                              hipStream_t stream)
{
    const float* n_embed   = (const float*)d_in[0];
    const float* e_embed   = (const float*)d_in[1];
    const int*   senders   = (const int*)d_in[2];
    const int*   receivers = (const int*)d_in[3];
    const float* W1        = (const float*)d_in[4];
    const float* b1        = (const float*)d_in[5];
    const float* W2        = (const float*)d_in[6];
    const float* b2        = (const float*)d_in[7];
    float* out = (float*)d_out;

    unsigned short* Ps = (unsigned short*)d_ws;             // [NN][192] bf16 (lane-packed)
    unsigned short* Pr = Ps + (size_t)NN * DH;              // [NN][192] bf16 (lane-packed)
    float*          invc = (float*)(Pr + (size_t)NN * DH);  // [NN] f32

    const int prep_items = FRAGS_TOT + NN * DO + NN;
    prep<<<(prep_items + 255) / 256, 256, 0, stream>>>(W1, W2, senders, out, invc);
    node_proj<<<dim3((NN + 63) / 64, 2), 256, 0, stream>>>(n_embed, b1, Ps);
    edge_mlp9<<<E_TOT / EB, 256, 0, stream>>>(
        e_embed, senders, receivers, Ps, Pr, b2, invc, out);
}